// Round 6
// baseline (247.159 us; speedup 1.0000x reference)
//
#include <hip/hip_runtime.h>
#include <hip/hip_bf16.h>

#define BB 8
#define NN 2048
#define DD 128
#define TI 16     // i-rows per block (both GEMM kernels)
#define JC 64     // j-rows per attention chunk
#define HP 132    // padded row stride (floats) for 128-wide LDS tiles

__device__ __forceinline__ float relu(float x) { return x > 0.f ? x : 0.f; }

// Kernel 0: WT[d][e] = W[e][d]  (64 KB, trivial)
__global__ __launch_bounds__(256) void GraphAttentionalLayer_1168231104632_tr(
    const float* __restrict__ W, float* __restrict__ WT)
{
    const int g = blockIdx.x * 256 + threadIdx.x;   // g = d*128 + e
    const int d = g >> 7, e = g & 127;
    WT[g] = W[e * DD + d];
}

// Kernel 1: hw[b,n,e] = sum_d h[b,n,d]*W[e,d];  E=exp(si), F=exp(sj).
// Block = (b, 16 rows); 128 threads; thread tile 4 rows x 4 e.
__global__ __launch_bounds__(128) void GraphAttentionalLayer_1168231104632_kernel(
    const float* __restrict__ h,
    const float* __restrict__ WT,     // transposed W: [d][e]
    const float* __restrict__ a,
    float* __restrict__ hw,
    float* __restrict__ E,
    float* __restrict__ F)
{
    __shared__ float h_s[TI][HP];     // 8.4 KB
    __shared__ float wt_s[32][HP];    // 16.9 KB (one d-tile of WT)

    const int t = threadIdx.x;
    const int tx = t & 31, ty = t >> 5;
    const int b = blockIdx.x >> 7;
    const int i0 = (blockIdx.x & 127) * TI;
    const size_t base = ((size_t)b * NN + i0) * DD;

    for (int r = 0; r < TI; r++)
        h_s[r][t] = h[base + (size_t)r * DD + t];

    const int e0 = tx * 4, r0 = ty * 4;
    float acc[4][4];
#pragma unroll
    for (int i = 0; i < 4; i++)
#pragma unroll
        for (int j = 0; j < 4; j++) acc[i][j] = 0.f;

    for (int dc = 0; dc < DD; dc += 32) {
        __syncthreads();   // protect prev tile (and publish h_s on first iter)
        for (int rr = 0; rr < 32; rr++)
            wt_s[rr][t] = WT[(size_t)(dc + rr) * DD + t];
        __syncthreads();
#pragma unroll 4
        for (int dd = 0; dd < 32; dd++) {
            const float4 wv = *reinterpret_cast<const float4*>(&wt_s[dd][e0]);
            const float w4[4] = {wv.x, wv.y, wv.z, wv.w};
#pragma unroll
            for (int r = 0; r < 4; r++) {
                const float hv = h_s[r0 + r][dc + dd];
#pragma unroll
                for (int e = 0; e < 4; e++) acc[r][e] += hv * w4[e];
            }
        }
    }

    // store hw tile (coalesced float4 per row)
#pragma unroll
    for (int r = 0; r < 4; r++) {
        float4 o = make_float4(acc[r][0], acc[r][1], acc[r][2], acc[r][3]);
        *reinterpret_cast<float4*>(&hw[base + (size_t)(r0 + r) * DD + e0]) = o;
    }

    // si/sj partials over this thread's 4 e's, reduce across the 32 tx lanes
    const float4 aiv = *reinterpret_cast<const float4*>(&a[e0]);
    const float4 ajv = *reinterpret_cast<const float4*>(&a[DD + e0]);
    const float ai4[4] = {aiv.x, aiv.y, aiv.z, aiv.w};
    const float aj4[4] = {ajv.x, ajv.y, ajv.z, ajv.w};
#pragma unroll
    for (int r = 0; r < 4; r++) {
        float pi = 0.f, pj = 0.f;
#pragma unroll
        for (int e = 0; e < 4; e++) { pi += acc[r][e] * ai4[e]; pj += acc[r][e] * aj4[e]; }
#pragma unroll
        for (int off = 16; off > 0; off >>= 1) {
            pi += __shfl_down(pi, off, 32);
            pj += __shfl_down(pj, off, 32);
        }
        if (tx == 0) {
            const size_t row = (size_t)b * NN + i0 + r0 + r;
            E[row] = __expf(pi);
            F[row] = __expf(pj);
        }
    }
}

// Kernel 2: w[i,j] = exp(relu(si+sj)) = max(E[i]*F[j], 1)   (exact identity)
//           out[b,i,:] = relu( (sum_j w*hw[b,j,:]) / sum_j w )
// Block = (b, 16 i); 128 threads; thread tile 4 i x 4 d; j in chunks of 64.
__global__ __launch_bounds__(128) void GraphAttentionalLayer_1168231104632_attn(
    const float* __restrict__ hw,
    const float* __restrict__ E,
    const float* __restrict__ F,
    float* __restrict__ out)
{
    __shared__ float hw_s[JC][HP];    // 33.8 KB
    __shared__ float w_s[TI][68];     // 4.4 KB (68: float4-aligned, 17 quads)
    __shared__ float E_s[TI];
    __shared__ float F_s[JC];

    const int t = threadIdx.x;
    const int tx = t & 31, ty = t >> 5;
    const int b = blockIdx.x >> 7;
    const int i0 = (blockIdx.x & 127) * TI;
    const size_t nb = (size_t)b * NN;

    if (t < TI) E_s[t] = E[nb + i0 + t];

    const int d0 = tx * 4, r0 = ty * 4;
    float acc[4][4];
    float z[4];
#pragma unroll
    for (int i = 0; i < 4; i++) {
        z[i] = 0.f;
#pragma unroll
        for (int j = 0; j < 4; j++) acc[i][j] = 0.f;
    }

    for (int jc = 0; jc < NN; jc += JC) {
        __syncthreads();   // protect previous chunk's reads (publishes E_s 1st iter)
        // stage hw chunk: JC*32 float4s, 16 per thread, coalesced
        for (int q = 0; q < 16; q++) {
            const int g = q * 128 + t;
            const int row = g >> 5, c4 = (g & 31) * 4;
            *reinterpret_cast<float4*>(&hw_s[row][c4]) =
                *reinterpret_cast<const float4*>(&hw[(nb + jc + row) * DD + c4]);
        }
        if (t < JC) F_s[t] = F[nb + jc + t];
        __syncthreads();
        // materialize weight tile: 16 x 64, 8 per thread
#pragma unroll
        for (int p = 0; p < 8; p++) {
            const int idx = p * 128 + t;
            const int ii = idx >> 6, jj = idx & 63;
            w_s[ii][jj] = fmaxf(E_s[ii] * F_s[jj], 1.0f);
        }
        __syncthreads();

        for (int jj = 0; jj < JC; jj += 4) {
            float wq[4][4], hq[4][4];
#pragma unroll
            for (int r = 0; r < 4; r++) {
                const float4 wv = *reinterpret_cast<const float4*>(&w_s[r0 + r][jj]);
                wq[r][0] = wv.x; wq[r][1] = wv.y; wq[r][2] = wv.z; wq[r][3] = wv.w;
            }
#pragma unroll
            for (int q = 0; q < 4; q++) {
                const float4 hv = *reinterpret_cast<const float4*>(&hw_s[jj + q][d0]);
                hq[q][0] = hv.x; hq[q][1] = hv.y; hq[q][2] = hv.z; hq[q][3] = hv.w;
            }
#pragma unroll
            for (int q = 0; q < 4; q++)
#pragma unroll
                for (int r = 0; r < 4; r++) {
                    const float wv = wq[r][q];
                    z[r] += wv;
#pragma unroll
                    for (int d = 0; d < 4; d++) acc[r][d] += wv * hq[q][d];
                }
        }
    }

    // epilogue: out = relu(acc / z)   (z >= 2048 > 0 always)
#pragma unroll
    for (int r = 0; r < 4; r++) {
        const float inv = 1.0f / z[r];
        float4 o;
        o.x = relu(acc[r][0] * inv);
        o.y = relu(acc[r][1] * inv);
        o.z = relu(acc[r][2] * inv);
        o.w = relu(acc[r][3] * inv);
        *reinterpret_cast<float4*>(&out[(nb + i0 + r0 + r) * DD + d0]) = o;
    }
}

extern "C" __attribute__((visibility("default")))
void kernel_launch(void* const* d_in, const int* in_sizes, int n_in,
                   void* d_out, int out_size, void* d_ws, size_t ws_size,
                   hipStream_t stream) {
    // All fp32, per the reference. Resolve by element count (robust to order):
    // h = 2,097,152; W = 16,384; a = 256.
    const float* h = nullptr; const float* W = nullptr; const float* a = nullptr;
    for (int i = 0; i < n_in; i++) {
        if (in_sizes[i] == BB * NN * DD)      h = (const float*)d_in[i];
        else if (in_sizes[i] == DD * DD)      W = (const float*)d_in[i];
        else if (in_sizes[i] == 2 * DD)       a = (const float*)d_in[i];
    }
    if (!h) h = (const float*)d_in[0];
    if (!W) W = (const float*)d_in[1];
    if (!a) a = (const float*)d_in[2];

    float* out = (float*)d_out;

    float* ws = (float*)d_ws;
    float* WT = ws;                                   // 16,384
    float* hw = WT + DD * DD;                         // 2,097,152
    float* E  = hw + (size_t)BB * NN * DD;            // 16,384
    float* F  = E + (size_t)BB * NN;                  // 16,384
    // total: 8,585,216 bytes of d_ws

    GraphAttentionalLayer_1168231104632_tr<<<(DD * DD) / 256, 256, 0, stream>>>(W, WT);
    GraphAttentionalLayer_1168231104632_kernel<<<BB * (NN / TI), 128, 0, stream>>>(h, WT, a, hw, E, F);
    GraphAttentionalLayer_1168231104632_attn<<<BB * (NN / TI), 128, 0, stream>>>(hw, E, F, out);
}

// Round 7
// 173.193 us; speedup vs baseline: 1.4271x; 1.4271x over previous
//
#include <hip/hip_runtime.h>
#include <hip/hip_bf16.h>

#define BB 8
#define NN 2048
#define DD 128
#define TI 16     // i-rows per block (hw GEMM)
#define HP 132    // padded row stride for 128-wide LDS tiles
#define SFS 2064  // row stride (floats) of SF array (2049 used)

__device__ __forceinline__ float relu(float x) { return x > 0.f ? x : 0.f; }

// ---------- Kernel 0: WT[d][e] = W[e][d] ----------
__global__ __launch_bounds__(256) void GraphAttentionalLayer_1168231104632_tr(
    const float* __restrict__ W, float* __restrict__ WT)
{
    const int g = blockIdx.x * 256 + threadIdx.x;   // g = d*128 + e
    const int d = g >> 7, e = g & 127;
    WT[g] = W[e * DD + d];
}

// ---------- Kernel 1: hw = h@W^T ; E=exp(si), F=exp(sj) ----------
// (unchanged from round 6 — verified correct)
__global__ __launch_bounds__(128) void GraphAttentionalLayer_1168231104632_kernel(
    const float* __restrict__ h,
    const float* __restrict__ WT,
    const float* __restrict__ a,
    float* __restrict__ hw,
    float* __restrict__ E,
    float* __restrict__ F)
{
    __shared__ float h_s[TI][HP];
    __shared__ float wt_s[32][HP];

    const int t = threadIdx.x;
    const int tx = t & 31, ty = t >> 5;
    const int b = blockIdx.x >> 7;
    const int i0 = (blockIdx.x & 127) * TI;
    const size_t base = ((size_t)b * NN + i0) * DD;

    for (int r = 0; r < TI; r++)
        h_s[r][t] = h[base + (size_t)r * DD + t];

    const int e0 = tx * 4, r0 = ty * 4;
    float acc[4][4];
#pragma unroll
    for (int i = 0; i < 4; i++)
#pragma unroll
        for (int j = 0; j < 4; j++) acc[i][j] = 0.f;

    for (int dc = 0; dc < DD; dc += 32) {
        __syncthreads();
        for (int rr = 0; rr < 32; rr++)
            wt_s[rr][t] = WT[(size_t)(dc + rr) * DD + t];
        __syncthreads();
#pragma unroll 4
        for (int dd = 0; dd < 32; dd++) {
            const float4 wv = *reinterpret_cast<const float4*>(&wt_s[dd][e0]);
            const float w4[4] = {wv.x, wv.y, wv.z, wv.w};
#pragma unroll
            for (int r = 0; r < 4; r++) {
                const float hv = h_s[r0 + r][dc + dd];
#pragma unroll
                for (int e = 0; e < 4; e++) acc[r][e] += hv * w4[e];
            }
        }
    }

#pragma unroll
    for (int r = 0; r < 4; r++) {
        float4 o = make_float4(acc[r][0], acc[r][1], acc[r][2], acc[r][3]);
        *reinterpret_cast<float4*>(&hw[base + (size_t)(r0 + r) * DD + e0]) = o;
    }

    const float4 aiv = *reinterpret_cast<const float4*>(&a[e0]);
    const float4 ajv = *reinterpret_cast<const float4*>(&a[DD + e0]);
    const float ai4[4] = {aiv.x, aiv.y, aiv.z, aiv.w};
    const float aj4[4] = {ajv.x, ajv.y, ajv.z, ajv.w};
#pragma unroll
    for (int r = 0; r < 4; r++) {
        float pi = 0.f, pj = 0.f;
#pragma unroll
        for (int e = 0; e < 4; e++) { pi += acc[r][e] * ai4[e]; pj += acc[r][e] * aj4[e]; }
#pragma unroll
        for (int off = 16; off > 0; off >>= 1) {
            pi += __shfl_down(pi, off, 32);
            pj += __shfl_down(pj, off, 32);
        }
        if (tx == 0) {
            const size_t row = (size_t)b * NN + i0 + r0 + r;
            E[row] = __expf(pi);
            F[row] = __expf(pj);
        }
    }
}

// ---------- Kernel 2: per-batch bitonic sort of F (ascending) + SF suffix sums ----------
__global__ __launch_bounds__(1024) void GraphAttentionalLayer_1168231104632_sort(
    const float* __restrict__ F,
    float* __restrict__ Fsorted,
    int* __restrict__ perm,
    float* __restrict__ SF)       // SF[b][k] = sum_{m>=k} Fsorted[m], k in [0,2048]
{
    __shared__ float kf[NN];
    __shared__ int   ki[NN];
    __shared__ float tmp[NN];

    const int t = threadIdx.x;
    const int b = blockIdx.x;
    const size_t nb = (size_t)b * NN;

    kf[t] = F[nb + t];           ki[t] = t;
    kf[t + 1024] = F[nb + t + 1024]; ki[t + 1024] = t + 1024;

    for (int k = 2; k <= NN; k <<= 1) {
        for (int j = k >> 1; j > 0; j >>= 1) {
            __syncthreads();
#pragma unroll
            for (int p = 0; p < 2; p++) {
                const int i = t + p * 1024;
                const int ixj = i ^ j;
                if (ixj > i) {
                    const bool up = ((i & k) == 0);
                    const float va = kf[i], vb = kf[ixj];
                    const bool swap = up ? (va > vb) : (va < vb);
                    if (swap) {
                        kf[i] = vb; kf[ixj] = va;
                        const int ta = ki[i]; ki[i] = ki[ixj]; ki[ixj] = ta;
                    }
                }
            }
        }
    }
    __syncthreads();

    Fsorted[nb + t] = kf[t];             perm[nb + t] = ki[t];
    Fsorted[nb + t + 1024] = kf[t + 1024]; perm[nb + t + 1024] = ki[t + 1024];

    // inclusive Hillis-Steele scan of kf (ping-pong with tmp)
    float* src = kf; float* dst = tmp;
    for (int off = 1; off < NN; off <<= 1) {
        __syncthreads();
#pragma unroll
        for (int p = 0; p < 2; p++) {
            const int i = t + p * 1024;
            dst[i] = src[i] + (i >= off ? src[i - off] : 0.f);
        }
        float* sw = src; src = dst; dst = sw;
    }
    __syncthreads();
    const float TF = src[NN - 1];
#pragma unroll
    for (int p = 0; p < 2; p++) {
        const int i = t + p * 1024;
        SF[(size_t)b * SFS + i] = TF - (i ? src[i - 1] : 0.f);
    }
    if (t == 0) SF[(size_t)b * SFS + NN] = 0.f;
}

// ---------- Kernel 3: chunked exclusive scans over sorted order ----------
// Q0L[m][d] local-exclusive prefix of hw[perm(m)][d]; Q1L of F*hw. Chunk=128.
__global__ __launch_bounds__(128) void GraphAttentionalLayer_1168231104632_scan(
    const float* __restrict__ hw,
    const float* __restrict__ Fsorted,
    const int* __restrict__ perm,
    float* __restrict__ Q0L, float* __restrict__ Q1L,
    float* __restrict__ C0,  float* __restrict__ C1)
{
    const int t = threadIdx.x;
    const int b = blockIdx.x >> 4, c = blockIdx.x & 15;
    const size_t nb = (size_t)b * NN;
    const int m0 = c * 128;

    float a0 = 0.f, a1 = 0.f;
    for (int mm = 0; mm < 128; mm++) {
        const int m = m0 + mm;
        const int j = perm[nb + m];
        const float Fv = Fsorted[nb + m];
        const float hv = hw[(nb + j) * DD + t];
        Q0L[(nb + m) * DD + t] = a0;
        Q1L[(nb + m) * DD + t] = a1;
        a0 += hv;
        a1 += Fv * hv;
    }
    C0[((size_t)b * 16 + c) * DD + t] = a0;
    C1[((size_t)b * 16 + c) * DD + t] = a1;
}

// ---------- Kernel 4: chunk-offset fixup (exclusive scan of chunk sums) ----------
__global__ __launch_bounds__(128) void GraphAttentionalLayer_1168231104632_fix(
    const float* __restrict__ C0, const float* __restrict__ C1,
    float* __restrict__ O0, float* __restrict__ O1)
{
    const int t = threadIdx.x;
    const int b = blockIdx.x;
    float o0 = 0.f, o1 = 0.f;
    for (int c = 0; c < 16; c++) {
        O0[((size_t)b * 17 + c) * DD + t] = o0;
        O1[((size_t)b * 17 + c) * DD + t] = o1;
        o0 += C0[((size_t)b * 16 + c) * DD + t];
        o1 += C1[((size_t)b * 16 + c) * DD + t];
    }
    O0[((size_t)b * 17 + 16) * DD + t] = o0;   // grand totals
    O1[((size_t)b * 17 + 16) * DD + t] = o1;
}

// ---------- Kernel 5: output ----------
// k_i = #{j : F_j < 1/E_i};  out[i,d] = relu((E_i*(T1-Q1[k])+Q0[k]) / (E_i*SF[k]+k))
__global__ __launch_bounds__(128) void GraphAttentionalLayer_1168231104632_out(
    const float* __restrict__ Q0L, const float* __restrict__ Q1L,
    const float* __restrict__ O0,  const float* __restrict__ O1,
    const float* __restrict__ Fsorted, const float* __restrict__ SF,
    const float* __restrict__ E, float* __restrict__ out)
{
    __shared__ float Fs_s[NN];        // 8 KB
    __shared__ float O0s[17][DD];     // 8.5 KB
    __shared__ float O1s[17][DD];     // 8.5 KB
    __shared__ float E_s[128];
    __shared__ float zinv_s[128];
    __shared__ int   k_s[128];

    const int t = threadIdx.x;
    const int b = blockIdx.x >> 4;
    const int i0 = (blockIdx.x & 15) * 128;
    const size_t nb = (size_t)b * NN;

    for (int q = 0; q < 16; q++) Fs_s[q * 128 + t] = Fsorted[nb + q * 128 + t];
    for (int c = 0; c < 17; c++) {
        O0s[c][t] = O0[((size_t)b * 17 + c) * DD + t];
        O1s[c][t] = O1[((size_t)b * 17 + c) * DD + t];
    }
    const float Ei = E[nb + i0 + t];
    E_s[t] = Ei;
    __syncthreads();

    // binary search: k = count of Fsorted < 1/Ei
    const float thr = 1.0f / Ei;
    int lo = 0, hi = NN;
    while (lo < hi) {
        const int mid = (lo + hi) >> 1;
        if (Fs_s[mid] < thr) lo = mid + 1; else hi = mid;
    }
    k_s[t] = lo;
    const float z = Ei * SF[(size_t)b * SFS + lo] + (float)lo;
    zinv_s[t] = 1.0f / z;
    __syncthreads();

    for (int ii = 0; ii < 128; ii++) {
        const int k = k_s[ii];
        const float Ev = E_s[ii], zv = zinv_s[ii];
        const float T1 = O1s[16][t];
        float num;
        if (k < NN) {
            const int c = k >> 7;
            const float q0 = Q0L[(nb + k) * DD + t] + O0s[c][t];
            const float q1 = Q1L[(nb + k) * DD + t] + O1s[c][t];
            num = Ev * (T1 - q1) + q0;
        } else {
            num = O0s[16][t];   // all-inactive: plain mean numerator
        }
        out[(nb + i0 + ii) * DD + t] = relu(num * zv);
    }
}

extern "C" __attribute__((visibility("default")))
void kernel_launch(void* const* d_in, const int* in_sizes, int n_in,
                   void* d_out, int out_size, void* d_ws, size_t ws_size,
                   hipStream_t stream) {
    const float* h = nullptr; const float* W = nullptr; const float* a = nullptr;
    for (int i = 0; i < n_in; i++) {
        if (in_sizes[i] == BB * NN * DD)      h = (const float*)d_in[i];
        else if (in_sizes[i] == DD * DD)      W = (const float*)d_in[i];
        else if (in_sizes[i] == 2 * DD)       a = (const float*)d_in[i];
    }
    if (!h) h = (const float*)d_in[0];
    if (!W) W = (const float*)d_in[1];
    if (!a) a = (const float*)d_in[2];

    float* out = (float*)d_out;
    float* ws = (float*)d_ws;

    // workspace layout (floats)
    float* WT   = ws;                              // 16,384
    float* hw   = WT + DD * DD;                    // 2,097,152
    float* E    = hw + (size_t)BB * NN * DD;       // 16,384
    float* F    = E + BB * NN;                     // 16,384
    float* Fs   = F + BB * NN;                     // 16,384
    float* SF   = Fs + BB * NN;                    // 8*2064 = 16,512
    int*   perm = (int*)(SF + BB * SFS);           // 16,384 ints
    float* Q0L  = (float*)(perm + BB * NN);        // 2,097,152
    float* Q1L  = Q0L + (size_t)BB * NN * DD;      // 2,097,152
    float* C0   = Q1L + (size_t)BB * NN * DD;      // 16,384
    float* C1   = C0 + BB * 16 * DD;               // 16,384
    float* O0   = C1 + BB * 16 * DD;               // 17,408
    float* O1   = O0 + BB * 17 * DD;               // 17,408
    const size_t need = (size_t)((O1 + BB * 17 * DD) - ws) * sizeof(float); // ~25.9 MB

    if (ws_size < need || d_ws == nullptr) {
        // diagnostic signature: absmax ~= 48 => workspace too small
        hipMemsetAsync(d_out, 0x42, (size_t)out_size * sizeof(float), stream);
        return;
    }

    GraphAttentionalLayer_1168231104632_tr<<<(DD * DD) / 256, 256, 0, stream>>>(W, WT);
    GraphAttentionalLayer_1168231104632_kernel<<<BB * (NN / TI), 128, 0, stream>>>(h, WT, a, hw, E, F);
    GraphAttentionalLayer_1168231104632_sort<<<BB, 1024, 0, stream>>>(F, Fs, perm, SF);
    GraphAttentionalLayer_1168231104632_scan<<<BB * 16, 128, 0, stream>>>(hw, Fs, perm, Q0L, Q1L, C0, C1);
    GraphAttentionalLayer_1168231104632_fix<<<BB, 128, 0, stream>>>(C0, C1, O0, O1);
    GraphAttentionalLayer_1168231104632_out<<<BB * 16, 128, 0, stream>>>(Q0L, Q1L, O0, O1, Fs, SF, E, out);
}

// Round 8
// 157.382 us; speedup vs baseline: 1.5704x; 1.1005x over previous
//
#include <hip/hip_runtime.h>
#include <hip/hip_bf16.h>

#define BB 8
#define NN 2048
#define DD 128
#define TI 16     // i-rows per block (hw GEMM)
#define HP 132    // padded row stride for 128-wide LDS tiles
#define CH 32     // scan chunk length (sorted rows per scan block)
#define NC (NN / CH)          // 64 chunks per batch
#define NO (NC + 1)           // 65 offset rows (incl. grand total)

__device__ __forceinline__ float relu(float x) { return x > 0.f ? x : 0.f; }

// ---------- Kernel 0: WT[d][e] = W[e][d] ----------
__global__ __launch_bounds__(256) void GraphAttentionalLayer_1168231104632_tr(
    const float* __restrict__ W, float* __restrict__ WT)
{
    const int g = blockIdx.x * 256 + threadIdx.x;   // g = d*128 + e
    const int d = g >> 7, e = g & 127;
    WT[g] = W[e * DD + d];
}

// ---------- Kernel 1: hw = h@W^T ; E=exp(si), F=exp(sj) ---------- (verified r6/r7)
__global__ __launch_bounds__(128) void GraphAttentionalLayer_1168231104632_kernel(
    const float* __restrict__ h,
    const float* __restrict__ WT,
    const float* __restrict__ a,
    float* __restrict__ hw,
    float* __restrict__ E,
    float* __restrict__ F)
{
    __shared__ float h_s[TI][HP];
    __shared__ float wt_s[32][HP];

    const int t = threadIdx.x;
    const int tx = t & 31, ty = t >> 5;
    const int b = blockIdx.x >> 7;
    const int i0 = (blockIdx.x & 127) * TI;
    const size_t base = ((size_t)b * NN + i0) * DD;

    for (int r = 0; r < TI; r++)
        h_s[r][t] = h[base + (size_t)r * DD + t];

    const int e0 = tx * 4, r0 = ty * 4;
    float acc[4][4];
#pragma unroll
    for (int i = 0; i < 4; i++)
#pragma unroll
        for (int j = 0; j < 4; j++) acc[i][j] = 0.f;

    for (int dc = 0; dc < DD; dc += 32) {
        __syncthreads();
        for (int rr = 0; rr < 32; rr++)
            wt_s[rr][t] = WT[(size_t)(dc + rr) * DD + t];
        __syncthreads();
#pragma unroll 4
        for (int dd = 0; dd < 32; dd++) {
            const float4 wv = *reinterpret_cast<const float4*>(&wt_s[dd][e0]);
            const float w4[4] = {wv.x, wv.y, wv.z, wv.w};
#pragma unroll
            for (int r = 0; r < 4; r++) {
                const float hv = h_s[r0 + r][dc + dd];
#pragma unroll
                for (int e = 0; e < 4; e++) acc[r][e] += hv * w4[e];
            }
        }
    }

#pragma unroll
    for (int r = 0; r < 4; r++) {
        float4 o = make_float4(acc[r][0], acc[r][1], acc[r][2], acc[r][3]);
        *reinterpret_cast<float4*>(&hw[base + (size_t)(r0 + r) * DD + e0]) = o;
    }

    const float4 aiv = *reinterpret_cast<const float4*>(&a[e0]);
    const float4 ajv = *reinterpret_cast<const float4*>(&a[DD + e0]);
    const float ai4[4] = {aiv.x, aiv.y, aiv.z, aiv.w};
    const float aj4[4] = {ajv.x, ajv.y, ajv.z, ajv.w};
#pragma unroll
    for (int r = 0; r < 4; r++) {
        float pi = 0.f, pj = 0.f;
#pragma unroll
        for (int e = 0; e < 4; e++) { pi += acc[r][e] * ai4[e]; pj += acc[r][e] * aj4[e]; }
#pragma unroll
        for (int off = 16; off > 0; off >>= 1) {
            pi += __shfl_down(pi, off, 32);
            pj += __shfl_down(pj, off, 32);
        }
        if (tx == 0) {
            const size_t row = (size_t)b * NN + i0 + r0 + r;
            E[row] = __expf(pi);
            F[row] = __expf(pj);
        }
    }
}

// ---------- Kernel 2: rank-sort (replaces bitonic) ----------
// rank(j) = #{m: F[m] < F[j]} + #{m < j: F[m] == F[j]}  -> exact permutation.
// Grid: BB*8 blocks x 256 threads (one thread per j).
__global__ __launch_bounds__(256) void GraphAttentionalLayer_1168231104632_rank(
    const float* __restrict__ F,
    float* __restrict__ Fsorted,
    int* __restrict__ perm)
{
    __shared__ float F_s[NN];

    const int t = threadIdx.x;
    const int b = blockIdx.x >> 3;
    const int j = (blockIdx.x & 7) * 256 + t;
    const size_t nb = (size_t)b * NN;

    for (int q = 0; q < NN / 256; q++)
        F_s[q * 256 + t] = F[nb + q * 256 + t];
    __syncthreads();

    const float fj = F_s[j];
    int cnt = 0;
#pragma unroll 8
    for (int m = 0; m < NN; m++) {
        const float fm = F_s[m];           // broadcast LDS read
        cnt += (fm < fj) | ((fm == fj) & (m < j));
    }
    Fsorted[nb + cnt] = fj;
    perm[nb + cnt] = j;
}

// ---------- Kernel 3: chunked exclusive scans over sorted order (chunk=32) ----------
__global__ __launch_bounds__(128) void GraphAttentionalLayer_1168231104632_scan(
    const float* __restrict__ hw,
    const float* __restrict__ Fsorted,
    const int* __restrict__ perm,
    float* __restrict__ Q0L, float* __restrict__ Q1L,
    float* __restrict__ C0,  float* __restrict__ C1)
{
    const int t = threadIdx.x;
    const int b = blockIdx.x / NC, c = blockIdx.x % NC;
    const size_t nb = (size_t)b * NN;
    const int m0 = c * CH;

    float a0 = 0.f, a1 = 0.f;
    for (int mm = 0; mm < CH; mm++) {
        const int m = m0 + mm;
        const int j = perm[nb + m];            // uniform -> scalar load
        const float Fv = Fsorted[nb + m];      // uniform
        const float hv = hw[(nb + j) * DD + t];
        Q0L[(nb + m) * DD + t] = a0;
        Q1L[(nb + m) * DD + t] = a1;
        a0 += hv;
        a1 += Fv * hv;
    }
    C0[((size_t)b * NC + c) * DD + t] = a0;
    C1[((size_t)b * NC + c) * DD + t] = a1;
}

// ---------- Kernel 4: chunk-offset fixup ----------
__global__ __launch_bounds__(128) void GraphAttentionalLayer_1168231104632_fix(
    const float* __restrict__ C0, const float* __restrict__ C1,
    float* __restrict__ O0, float* __restrict__ O1)
{
    const int t = threadIdx.x;
    const int b = blockIdx.x;
    float o0 = 0.f, o1 = 0.f;
    for (int c = 0; c < NC; c++) {
        O0[((size_t)b * NO + c) * DD + t] = o0;
        O1[((size_t)b * NO + c) * DD + t] = o1;
        o0 += C0[((size_t)b * NC + c) * DD + t];
        o1 += C1[((size_t)b * NC + c) * DD + t];
    }
    O0[((size_t)b * NO + NC) * DD + t] = o0;   // grand totals
    O1[((size_t)b * NO + NC) * DD + t] = o1;
}

// ---------- Kernel 5: SF suffix-scan + k binary search + zinv (fused) ----------
// One block per batch; 1024 threads, 2 i's each.
__global__ __launch_bounds__(1024) void GraphAttentionalLayer_1168231104632_kz(
    const float* __restrict__ Fsorted,
    const float* __restrict__ E,
    int* __restrict__ kk,
    float* __restrict__ zinv)
{
    __shared__ float fs_s[NN];
    __shared__ float p0[NN];
    __shared__ float p1[NN];

    const int t = threadIdx.x;
    const int b = blockIdx.x;
    const size_t nb = (size_t)b * NN;

#pragma unroll
    for (int p = 0; p < 2; p++) {
        const int i = t + p * 1024;
        const float v = Fsorted[nb + i];
        fs_s[i] = v;
        p0[i] = v;
    }

    // inclusive Hillis-Steele scan (11 stages, ping-pong p0/p1)
    float* src = p0; float* dst = p1;
    for (int off = 1; off < NN; off <<= 1) {
        __syncthreads();
#pragma unroll
        for (int p = 0; p < 2; p++) {
            const int i = t + p * 1024;
            dst[i] = src[i] + (i >= off ? src[i - off] : 0.f);
        }
        float* sw = src; src = dst; dst = sw;
    }
    __syncthreads();
    const float TF = src[NN - 1];

#pragma unroll
    for (int p = 0; p < 2; p++) {
        const int i = t + p * 1024;
        const float Ei = E[nb + i];
        const float thr = 1.0f / Ei;
        int lo = 0, hi = NN;
        while (lo < hi) {
            const int mid = (lo + hi) >> 1;
            if (fs_s[mid] < thr) lo = mid + 1; else hi = mid;
        }
        const float SFk = TF - (lo ? src[lo - 1] : 0.f);   // suffix sum over active set
        const float z = Ei * SFk + (float)lo;
        kk[nb + i] = lo;
        zinv[nb + i] = 1.0f / z;
    }
}

// ---------- Kernel 6: output (one block per i-row, fully parallel) ----------
__global__ __launch_bounds__(128) void GraphAttentionalLayer_1168231104632_out(
    const float* __restrict__ Q0L, const float* __restrict__ Q1L,
    const float* __restrict__ O0,  const float* __restrict__ O1,
    const int* __restrict__ kk,    const float* __restrict__ zinv,
    const float* __restrict__ E,   float* __restrict__ out)
{
    const int t = threadIdx.x;
    const int row = blockIdx.x;          // 0 .. BB*NN-1
    const int b = row >> 11;
    const size_t nb = (size_t)b * NN;

    const int k = kk[row];               // uniform
    const float Ev = E[row];
    const float zv = zinv[row];
    const float T1 = O1[((size_t)b * NO + NC) * DD + t];

    float num;
    if (k < NN) {
        const int c = k >> 5;
        const float q0 = Q0L[(nb + k) * DD + t] + O0[((size_t)b * NO + c) * DD + t];
        const float q1 = Q1L[(nb + k) * DD + t] + O1[((size_t)b * NO + c) * DD + t];
        num = Ev * (T1 - q1) + q0;
    } else {
        num = O0[((size_t)b * NO + NC) * DD + t];   // all weights = 1
    }
    out[(size_t)row * DD + t] = relu(num * zv);
}

extern "C" __attribute__((visibility("default")))
void kernel_launch(void* const* d_in, const int* in_sizes, int n_in,
                   void* d_out, int out_size, void* d_ws, size_t ws_size,
                   hipStream_t stream) {
    const float* h = nullptr; const float* W = nullptr; const float* a = nullptr;
    for (int i = 0; i < n_in; i++) {
        if (in_sizes[i] == BB * NN * DD)      h = (const float*)d_in[i];
        else if (in_sizes[i] == DD * DD)      W = (const float*)d_in[i];
        else if (in_sizes[i] == 2 * DD)       a = (const float*)d_in[i];
    }
    if (!h) h = (const float*)d_in[0];
    if (!W) W = (const float*)d_in[1];
    if (!a) a = (const float*)d_in[2];

    float* out = (float*)d_out;
    float* ws = (float*)d_ws;

    // workspace layout (floats / ints)
    float* WT   = ws;                              // 16,384
    float* hw   = WT + DD * DD;                    // 2,097,152
    float* E    = hw + (size_t)BB * NN * DD;       // 16,384
    float* F    = E + BB * NN;                     // 16,384
    float* Fs   = F + BB * NN;                     // 16,384
    float* zinv = Fs + BB * NN;                    // 16,384
    int*   perm = (int*)(zinv + BB * NN);          // 16,384
    int*   kk   = perm + BB * NN;                  // 16,384
    float* Q0L  = (float*)(kk + BB * NN);          // 2,097,152
    float* Q1L  = Q0L + (size_t)BB * NN * DD;      // 2,097,152
    float* C0   = Q1L + (size_t)BB * NN * DD;      // 65,536
    float* C1   = C0 + BB * NC * DD;               // 65,536
    float* O0   = C1 + BB * NC * DD;               // 66,560
    float* O1   = O0 + BB * NO * DD;               // 66,560
    const size_t need = (size_t)((O1 + BB * NO * DD) - ws) * sizeof(float); // ~26.7 MB

    if (ws_size < need || d_ws == nullptr) {
        // diagnostic signature: absmax ~= 48 => workspace too small
        hipMemsetAsync(d_out, 0x42, (size_t)out_size * sizeof(float), stream);
        return;
    }

    GraphAttentionalLayer_1168231104632_tr<<<(DD * DD) / 256, 256, 0, stream>>>(W, WT);
    GraphAttentionalLayer_1168231104632_kernel<<<BB * (NN / TI), 128, 0, stream>>>(h, WT, a, hw, E, F);
    GraphAttentionalLayer_1168231104632_rank<<<BB * 8, 256, 0, stream>>>(F, Fs, perm);
    GraphAttentionalLayer_1168231104632_scan<<<BB * NC, 128, 0, stream>>>(hw, Fs, perm, Q0L, Q1L, C0, C1);
    GraphAttentionalLayer_1168231104632_fix<<<BB, 128, 0, stream>>>(C0, C1, O0, O1);
    GraphAttentionalLayer_1168231104632_kz<<<BB, 1024, 0, stream>>>(Fs, E, kk, zinv);
    GraphAttentionalLayer_1168231104632_out<<<BB * NN, 128, 0, stream>>>(Q0L, Q1L, O0, O1, kk, zinv, E, out);
}

// Round 9
// 114.913 us; speedup vs baseline: 2.1508x; 1.3696x over previous
//
#include <hip/hip_runtime.h>
#include <hip/hip_bf16.h>

#define BB 8
#define NN 2048
#define DD 128
#define TI 16     // i-rows per block (hw GEMM)
#define HP 132    // padded row stride for 128-wide LDS tiles
#define CH 32     // scan chunk length (sorted rows per scan block)
#define NC (NN / CH)          // 64 chunks per batch
#define NO (NC + 1)           // 65 offset rows (incl. grand total)

__device__ __forceinline__ float relu(float x) { return x > 0.f ? x : 0.f; }

// ---------- Kernel 0: WT[d][e] = W[e][d] ----------
__global__ __launch_bounds__(256) void GraphAttentionalLayer_1168231104632_tr(
    const float* __restrict__ W, float* __restrict__ WT)
{
    const int g = blockIdx.x * 256 + threadIdx.x;   // g = d*128 + e
    const int d = g >> 7, e = g & 127;
    WT[g] = W[e * DD + d];
}

// ---------- Kernel 1: hw = h@W^T ; E=exp(si), F=exp(sj) ---------- (verified r6-r8)
__global__ __launch_bounds__(128) void GraphAttentionalLayer_1168231104632_kernel(
    const float* __restrict__ h,
    const float* __restrict__ WT,
    const float* __restrict__ a,
    float* __restrict__ hw,
    float* __restrict__ E,
    float* __restrict__ F)
{
    __shared__ float h_s[TI][HP];
    __shared__ float wt_s[32][HP];

    const int t = threadIdx.x;
    const int tx = t & 31, ty = t >> 5;
    const int b = blockIdx.x >> 7;
    const int i0 = (blockIdx.x & 127) * TI;
    const size_t base = ((size_t)b * NN + i0) * DD;

    for (int r = 0; r < TI; r++)
        h_s[r][t] = h[base + (size_t)r * DD + t];

    const int e0 = tx * 4, r0 = ty * 4;
    float acc[4][4];
#pragma unroll
    for (int i = 0; i < 4; i++)
#pragma unroll
        for (int j = 0; j < 4; j++) acc[i][j] = 0.f;

    for (int dc = 0; dc < DD; dc += 32) {
        __syncthreads();
        for (int rr = 0; rr < 32; rr++)
            wt_s[rr][t] = WT[(size_t)(dc + rr) * DD + t];
        __syncthreads();
#pragma unroll 4
        for (int dd = 0; dd < 32; dd++) {
            const float4 wv = *reinterpret_cast<const float4*>(&wt_s[dd][e0]);
            const float w4[4] = {wv.x, wv.y, wv.z, wv.w};
#pragma unroll
            for (int r = 0; r < 4; r++) {
                const float hv = h_s[r0 + r][dc + dd];
#pragma unroll
                for (int e = 0; e < 4; e++) acc[r][e] += hv * w4[e];
            }
        }
    }

#pragma unroll
    for (int r = 0; r < 4; r++) {
        float4 o = make_float4(acc[r][0], acc[r][1], acc[r][2], acc[r][3]);
        *reinterpret_cast<float4*>(&hw[base + (size_t)(r0 + r) * DD + e0]) = o;
    }

    const float4 aiv = *reinterpret_cast<const float4*>(&a[e0]);
    const float4 ajv = *reinterpret_cast<const float4*>(&a[DD + e0]);
    const float ai4[4] = {aiv.x, aiv.y, aiv.z, aiv.w};
    const float aj4[4] = {ajv.x, ajv.y, ajv.z, ajv.w};
#pragma unroll
    for (int r = 0; r < 4; r++) {
        float pi = 0.f, pj = 0.f;
#pragma unroll
        for (int e = 0; e < 4; e++) { pi += acc[r][e] * ai4[e]; pj += acc[r][e] * aj4[e]; }
#pragma unroll
        for (int off = 16; off > 0; off >>= 1) {
            pi += __shfl_down(pi, off, 32);
            pj += __shfl_down(pj, off, 32);
        }
        if (tx == 0) {
            const size_t row = (size_t)b * NN + i0 + r0 + r;
            E[row] = __expf(pi);
            F[row] = __expf(pj);
        }
    }
}

// ---------- Kernel 2: rank-sort, cooperative ----------
// rank(j) = #{m: F[m] < F[j]} + #{m < j: F[m] == F[j]}.
// Grid: BB*32 blocks x 256 threads. Block owns 64 j's; 4 threads per j, each
// counting a 512-element m-slice from LDS; LDS reduce; wave 0 scatters.
__global__ __launch_bounds__(256) void GraphAttentionalLayer_1168231104632_rank(
    const float* __restrict__ F,
    float* __restrict__ Fsorted,
    int* __restrict__ perm)
{
    __shared__ float F_s[NN];
    __shared__ int   part[4][64];

    const int t = threadIdx.x;
    const int b = blockIdx.x >> 5;               // 32 blocks per batch
    const int j0 = (blockIdx.x & 31) * 64;
    const size_t nb = (size_t)b * NN;

    for (int q = 0; q < NN / 256; q++)
        F_s[q * 256 + t] = F[nb + q * 256 + t];
    __syncthreads();

    const int tj = t & 63, ts = t >> 6;          // wave ts handles slice ts
    const int j = j0 + tj;
    const float fj = F_s[j];
    const int m0 = ts * (NN / 4);
    int cnt = 0;
#pragma unroll 8
    for (int mi = 0; mi < NN / 4; mi++) {
        const int m = m0 + mi;
        const float fm = F_s[m];                 // wave-broadcast LDS read
        cnt += (fm < fj) | ((fm == fj) & (m < j));
    }
    part[ts][tj] = cnt;
    __syncthreads();
    if (ts == 0) {
        const int r = part[0][tj] + part[1][tj] + part[2][tj] + part[3][tj];
        Fsorted[nb + r] = fj;
        perm[nb + r] = j;
    }
}

// ---------- Kernel 3: chunked exclusive scans (ILP preload) ----------
__global__ __launch_bounds__(128) void GraphAttentionalLayer_1168231104632_scan(
    const float* __restrict__ hw,
    const float* __restrict__ Fsorted,
    const int* __restrict__ perm,
    float* __restrict__ Q0L, float* __restrict__ Q1L,
    float* __restrict__ C0,  float* __restrict__ C1)
{
    const int t = threadIdx.x;
    const int b = blockIdx.x / NC, c = blockIdx.x % NC;
    const size_t nb = (size_t)b * NN;
    const int m0 = c * CH;

    // uniform metadata (scalarized by compiler)
    int   jv[CH];
    float Fv[CH];
#pragma unroll
    for (int mm = 0; mm < CH; mm++) jv[mm] = perm[nb + m0 + mm];
#pragma unroll
    for (int mm = 0; mm < CH; mm++) Fv[mm] = Fsorted[nb + m0 + mm];

    // 32 independent gathered row-loads (ILP hides latency)
    float hv[CH];
#pragma unroll
    for (int mm = 0; mm < CH; mm++)
        hv[mm] = hw[(nb + jv[mm]) * DD + t];

    float a0 = 0.f, a1 = 0.f;
#pragma unroll
    for (int mm = 0; mm < CH; mm++) {
        const int m = m0 + mm;
        Q0L[(nb + m) * DD + t] = a0;
        Q1L[(nb + m) * DD + t] = a1;
        a0 += hv[mm];
        a1 += Fv[mm] * hv[mm];
    }
    C0[((size_t)b * NC + c) * DD + t] = a0;
    C1[((size_t)b * NC + c) * DD + t] = a1;
}

// ---------- Kernel 4: chunk-offset fixup (ILP in groups of 16) ----------
__global__ __launch_bounds__(128) void GraphAttentionalLayer_1168231104632_fix(
    const float* __restrict__ C0, const float* __restrict__ C1,
    float* __restrict__ O0, float* __restrict__ O1)
{
    const int t = threadIdx.x;
    const int b = blockIdx.x;
    float o0 = 0.f, o1 = 0.f;
    for (int cc = 0; cc < NC; cc += 16) {
        float c0[16], c1[16];
#pragma unroll
        for (int q = 0; q < 16; q++) {
            c0[q] = C0[((size_t)b * NC + cc + q) * DD + t];
            c1[q] = C1[((size_t)b * NC + cc + q) * DD + t];
        }
#pragma unroll
        for (int q = 0; q < 16; q++) {
            O0[((size_t)b * NO + cc + q) * DD + t] = o0;
            O1[((size_t)b * NO + cc + q) * DD + t] = o1;
            o0 += c0[q];
            o1 += c1[q];
        }
    }
    O0[((size_t)b * NO + NC) * DD + t] = o0;   // grand totals
    O1[((size_t)b * NO + NC) * DD + t] = o1;
}

// ---------- Kernel 5: SF suffix-scan + k binary search + zinv ----------
__global__ __launch_bounds__(1024) void GraphAttentionalLayer_1168231104632_kz(
    const float* __restrict__ Fsorted,
    const float* __restrict__ E,
    int* __restrict__ kk,
    float* __restrict__ zinv)
{
    __shared__ float fs_s[NN];
    __shared__ float p0[NN];
    __shared__ float p1[NN];

    const int t = threadIdx.x;
    const int b = blockIdx.x;
    const size_t nb = (size_t)b * NN;

#pragma unroll
    for (int p = 0; p < 2; p++) {
        const int i = t + p * 1024;
        const float v = Fsorted[nb + i];
        fs_s[i] = v;
        p0[i] = v;
    }

    float* src = p0; float* dst = p1;
    for (int off = 1; off < NN; off <<= 1) {
        __syncthreads();
#pragma unroll
        for (int p = 0; p < 2; p++) {
            const int i = t + p * 1024;
            dst[i] = src[i] + (i >= off ? src[i - off] : 0.f);
        }
        float* sw = src; src = dst; dst = sw;
    }
    __syncthreads();
    const float TF = src[NN - 1];

#pragma unroll
    for (int p = 0; p < 2; p++) {
        const int i = t + p * 1024;
        const float Ei = E[nb + i];
        const float thr = 1.0f / Ei;
        int lo = 0, hi = NN;
        while (lo < hi) {
            const int mid = (lo + hi) >> 1;
            if (fs_s[mid] < thr) lo = mid + 1; else hi = mid;
        }
        const float SFk = TF - (lo ? src[lo - 1] : 0.f);
        const float z = Ei * SFk + (float)lo;
        kk[nb + i] = lo;
        zinv[nb + i] = 1.0f / z;
    }
}

// ---------- Kernel 6: output (one block per i-row) ----------
__global__ __launch_bounds__(128) void GraphAttentionalLayer_1168231104632_out(
    const float* __restrict__ Q0L, const float* __restrict__ Q1L,
    const float* __restrict__ O0,  const float* __restrict__ O1,
    const int* __restrict__ kk,    const float* __restrict__ zinv,
    const float* __restrict__ E,   float* __restrict__ out)
{
    const int t = threadIdx.x;
    const int row = blockIdx.x;          // 0 .. BB*NN-1
    const int b = row >> 11;
    const size_t nb = (size_t)b * NN;

    const int k = kk[row];               // uniform
    const float Ev = E[row];
    const float zv = zinv[row];
    const float T1 = O1[((size_t)b * NO + NC) * DD + t];

    float num;
    if (k < NN) {
        const int c = k >> 5;
        const float q0 = Q0L[(nb + k) * DD + t] + O0[((size_t)b * NO + c) * DD + t];
        const float q1 = Q1L[(nb + k) * DD + t] + O1[((size_t)b * NO + c) * DD + t];
        num = Ev * (T1 - q1) + q0;
    } else {
        num = O0[((size_t)b * NO + NC) * DD + t];
    }
    out[(size_t)row * DD + t] = relu(num * zv);
}

extern "C" __attribute__((visibility("default")))
void kernel_launch(void* const* d_in, const int* in_sizes, int n_in,
                   void* d_out, int out_size, void* d_ws, size_t ws_size,
                   hipStream_t stream) {
    const float* h = nullptr; const float* W = nullptr; const float* a = nullptr;
    for (int i = 0; i < n_in; i++) {
        if (in_sizes[i] == BB * NN * DD)      h = (const float*)d_in[i];
        else if (in_sizes[i] == DD * DD)      W = (const float*)d_in[i];
        else if (in_sizes[i] == 2 * DD)       a = (const float*)d_in[i];
    }
    if (!h) h = (const float*)d_in[0];
    if (!W) W = (const float*)d_in[1];
    if (!a) a = (const float*)d_in[2];

    float* out = (float*)d_out;
    float* ws = (float*)d_ws;

    float* WT   = ws;                              // 16,384
    float* hw   = WT + DD * DD;                    // 2,097,152
    float* E    = hw + (size_t)BB * NN * DD;       // 16,384
    float* F    = E + BB * NN;                     // 16,384
    float* Fs   = F + BB * NN;                     // 16,384
    float* zinv = Fs + BB * NN;                    // 16,384
    int*   perm = (int*)(zinv + BB * NN);          // 16,384
    int*   kk   = perm + BB * NN;                  // 16,384
    float* Q0L  = (float*)(kk + BB * NN);          // 2,097,152
    float* Q1L  = Q0L + (size_t)BB * NN * DD;      // 2,097,152
    float* C0   = Q1L + (size_t)BB * NN * DD;      // 65,536
    float* C1   = C0 + BB * NC * DD;               // 65,536
    float* O0   = C1 + BB * NC * DD;               // 66,560
    float* O1   = O0 + BB * NO * DD;               // 66,560
    const size_t need = (size_t)((O1 + BB * NO * DD) - ws) * sizeof(float); // ~26.7 MB

    if (ws_size < need || d_ws == nullptr) {
        hipMemsetAsync(d_out, 0x42, (size_t)out_size * sizeof(float), stream);
        return;
    }

    GraphAttentionalLayer_1168231104632_tr<<<(DD * DD) / 256, 256, 0, stream>>>(W, WT);
    GraphAttentionalLayer_1168231104632_kernel<<<BB * (NN / TI), 128, 0, stream>>>(h, WT, a, hw, E, F);
    GraphAttentionalLayer_1168231104632_rank<<<BB * 32, 256, 0, stream>>>(F, Fs, perm);
    GraphAttentionalLayer_1168231104632_scan<<<BB * NC, 128, 0, stream>>>(hw, Fs, perm, Q0L, Q1L, C0, C1);
    GraphAttentionalLayer_1168231104632_fix<<<BB, 128, 0, stream>>>(C0, C1, O0, O1);
    GraphAttentionalLayer_1168231104632_kz<<<BB, 1024, 0, stream>>>(Fs, E, kk, zinv);
    GraphAttentionalLayer_1168231104632_out<<<BB * NN, 128, 0, stream>>>(Q0L, Q1L, O0, O1, kk, zinv, E, out);
}